// Round 18
// baseline (51.094 us; speedup 1.0000x reference)
//
#include <hip/hip_runtime.h>
#include <hip/hip_bf16.h>
#include <stdint.h>

#define H 512
#define W 512
#define HW (H * W)
#define RPP 256           // row-pairs per image (k_mm granularity)

typedef float f32x4 __attribute__((ext_vector_type(4)));

__device__ __forceinline__ int refl(int i, int n) {
    // BORDER_REFLECT_101: -1 -> 1, n -> n-2
    return i < 0 ? -i : (i >= n ? 2 * n - 2 - i : i);
}

// Inline-asm 16B load: compiler cannot narrow it or re-serialize the batch.
__device__ __forceinline__ f32x4 gload4(const f32x4* p) {
    f32x4 d;
    asm volatile("global_load_dwordx4 %0, %1, off" : "=v"(d) : "v"(p) : "memory");
    return d;
}

// quantized gray (floor == uint8 trunc for [0,255]) for 8 px from 6 f32x4s
// (L[0],L[1]=R; L[2],L[3]=G; L[4],L[5]=B). Bit-identical expression in both passes.
__device__ __forceinline__ void gray8x(const f32x4* __restrict__ L, float* __restrict__ g) {
    g[0] = floorf((0.2989f * L[0].x + 0.587f * L[2].x + 0.114f * L[4].x) * 255.0f);
    g[1] = floorf((0.2989f * L[0].y + 0.587f * L[2].y + 0.114f * L[4].y) * 255.0f);
    g[2] = floorf((0.2989f * L[0].z + 0.587f * L[2].z + 0.114f * L[4].z) * 255.0f);
    g[3] = floorf((0.2989f * L[0].w + 0.587f * L[2].w + 0.114f * L[4].w) * 255.0f);
    g[4] = floorf((0.2989f * L[1].x + 0.587f * L[3].x + 0.114f * L[5].x) * 255.0f);
    g[5] = floorf((0.2989f * L[1].y + 0.587f * L[3].y + 0.114f * L[5].y) * 255.0f);
    g[6] = floorf((0.2989f * L[1].z + 0.587f * L[3].z + 0.114f * L[5].z) * 255.0f);
    g[7] = floorf((0.2989f * L[1].w + 0.587f * L[3].w + 0.114f * L[5].w) * 255.0f);
}

// float4-based variant for k_loss (identical FP expression)
__device__ __forceinline__ void gray8f(float4 ra, float4 rb, float4 ga, float4 gb,
                                       float4 ba, float4 bb, float* __restrict__ g) {
    g[0] = floorf((0.2989f * ra.x + 0.587f * ga.x + 0.114f * ba.x) * 255.0f);
    g[1] = floorf((0.2989f * ra.y + 0.587f * ga.y + 0.114f * ba.y) * 255.0f);
    g[2] = floorf((0.2989f * ra.z + 0.587f * ga.z + 0.114f * ba.z) * 255.0f);
    g[3] = floorf((0.2989f * ra.w + 0.587f * ga.w + 0.114f * ba.w) * 255.0f);
    g[4] = floorf((0.2989f * rb.x + 0.587f * gb.x + 0.114f * bb.x) * 255.0f);
    g[5] = floorf((0.2989f * rb.y + 0.587f * gb.y + 0.114f * bb.y) * 255.0f);
    g[6] = floorf((0.2989f * rb.z + 0.587f * gb.z + 0.114f * bb.z) * 255.0f);
    g[7] = floorf((0.2989f * rb.w + 0.587f * gb.w + 0.114f * bb.w) * 255.0f);
}

__device__ __forceinline__ void grayrow(const float4* __restrict__ p4, int row, int lane,
                                        float* __restrict__ g) {
    int o = row * (W / 4) + lane * 2;
    float4 ra = p4[o],                 rb = p4[o + 1];
    float4 ga = p4[o + HW / 4],        gb = p4[o + 1 + HW / 4];
    float4 ba = p4[o + 2 * (HW / 4)],  bb = p4[o + 1 + 2 * (HW / 4)];
    gray8f(ra, rb, ga, gb, ba, bb, g);
}

// 10-col halo-extended window from this lane's 8 gray px via shuffles.
__device__ __forceinline__ void win10(const float* __restrict__ g, int lane,
                                      float* __restrict__ h) {
    #pragma unroll
    for (int j = 0; j < 8; ++j) h[j + 1] = g[j];
    float up = __shfl_up(g[7], 1);
    float dn = __shfl_down(g[0], 1);
    h[0] = (lane == 0)  ? g[1] : up;   // x=-1  -> x=1
    h[9] = (lane == 63) ? g[6] : dn;   // x=512 -> x=510
}

__device__ __forceinline__ void sobel8(const float* __restrict__ hm,
                                       const float* __restrict__ h0,
                                       const float* __restrict__ hp,
                                       float* __restrict__ mag) {
    float sx[10], sy[10];
    #pragma unroll
    for (int j = 0; j < 10; ++j) {
        sx[j] = hm[j] + 2.0f * h0[j] + hp[j];
        sy[j] = hp[j] - hm[j];
    }
    #pragma unroll
    for (int k = 0; k < 8; ++k) {
        float gx = sx[k + 2] - sx[k];
        float gy = sy[k] + 2.0f * sy[k + 1] + sy[k + 2];
        mag[k] = sqrtf(gx * gx + gy * gy);
    }
}

// ---------------- K1: 2-ROW sobel min/max from RGB, split-wait asm batch ------------
// One wave = rows (y0, y0+1) of one source: 24 asm loads (rows y0-1..y0+2 x 3ch)
// issued back-to-back; vmcnt(12)/(6)/(0) split waits overlap gray/sobel compute
// with in-flight loads. 2 sobels amortize the wave's fixed costs (k_loss shape).
__global__ __launch_bounds__(256, 2) void k_mm(const float* __restrict__ vis,
                                               const float* __restrict__ ir,
                                               float* __restrict__ pm, int B) {
    int lane = threadIdx.x & 63;
    int nwg = gridDim.x;
    int bid = (blockIdx.x & 7) * (nwg >> 3) + (blockIdx.x >> 3);  // bijective (nwg%8==0)
    int task = bid * 4 + (threadIdx.x >> 6);    // [0, 2*B*RPP)
    int per_src = B * RPP;                      // 4096
    int src = task >= per_src;
    int rem = src ? task - per_src : task;
    int b  = rem >> 8;
    int rp = rem & 255;
    int y0 = rp * 2;
    const f32x4* p4 = (const f32x4*)((src ? ir : vis) + (size_t)b * 3 * HW);

    int om = refl(y0 - 1, H) * (W / 4) + lane * 2;
    int o0 = y0 * (W / 4) + lane * 2;
    int o1 = (y0 + 1) * (W / 4) + lane * 2;
    int op = refl(y0 + 2, H) * (W / 4) + lane * 2;

    f32x4 L[24];
    // row y0-1
    L[0]  = gload4(p4 + om);
    L[1]  = gload4(p4 + om + 1);
    L[2]  = gload4(p4 + om + HW / 4);
    L[3]  = gload4(p4 + om + 1 + HW / 4);
    L[4]  = gload4(p4 + om + 2 * (HW / 4));
    L[5]  = gload4(p4 + om + 1 + 2 * (HW / 4));
    // row y0
    L[6]  = gload4(p4 + o0);
    L[7]  = gload4(p4 + o0 + 1);
    L[8]  = gload4(p4 + o0 + HW / 4);
    L[9]  = gload4(p4 + o0 + 1 + HW / 4);
    L[10] = gload4(p4 + o0 + 2 * (HW / 4));
    L[11] = gload4(p4 + o0 + 1 + 2 * (HW / 4));
    // row y0+1
    L[12] = gload4(p4 + o1);
    L[13] = gload4(p4 + o1 + 1);
    L[14] = gload4(p4 + o1 + HW / 4);
    L[15] = gload4(p4 + o1 + 1 + HW / 4);
    L[16] = gload4(p4 + o1 + 2 * (HW / 4));
    L[17] = gload4(p4 + o1 + 1 + 2 * (HW / 4));
    // row y0+2
    L[18] = gload4(p4 + op);
    L[19] = gload4(p4 + op + 1);
    L[20] = gload4(p4 + op + HW / 4);
    L[21] = gload4(p4 + op + 1 + HW / 4);
    L[22] = gload4(p4 + op + 2 * (HW / 4));
    L[23] = gload4(p4 + op + 1 + 2 * (HW / 4));

    // rows y0-1, y0 complete; y0+1, y0+2 still in flight
    asm volatile("s_waitcnt vmcnt(12)" ::: "memory");
    __builtin_amdgcn_sched_barrier(0);
    float gm[8], g0[8];
    gray8x(&L[0], gm);
    gray8x(&L[6], g0);
    float hm[10], h0[10];
    win10(gm, lane, hm);
    win10(g0, lane, h0);

    // row y0+1 complete
    asm volatile("s_waitcnt vmcnt(6)" ::: "memory");
    __builtin_amdgcn_sched_barrier(0);
    float g1[8];
    gray8x(&L[12], g1);
    float h1[10];
    win10(g1, lane, h1);
    float mag0[8];
    sobel8(hm, h0, h1, mag0);

    // row y0+2 complete
    asm volatile("s_waitcnt vmcnt(0)" ::: "memory");
    __builtin_amdgcn_sched_barrier(0);
    float gp[8];
    gray8x(&L[18], gp);
    float hp[10];
    win10(gp, lane, hp);
    float mag1[8];
    sobel8(h0, h1, hp, mag1);

    float mn = fminf(mag0[0], mag1[0]), mx = fmaxf(mag0[0], mag1[0]);
    #pragma unroll
    for (int k = 1; k < 8; ++k) {
        mn = fminf(mn, fminf(mag0[k], mag1[k]));
        mx = fmaxf(mx, fmaxf(mag0[k], mag1[k]));
    }
    #pragma unroll
    for (int o = 32; o > 0; o >>= 1) {
        mn = fminf(mn, __shfl_down(mn, o));
        mx = fmaxf(mx, __shfl_down(mx, o));
    }
    if (lane == 0) {
        float* o = pm + ((size_t)(src * B + b) * RPP + rp) * 2;
        o[0] = mn;
        o[1] = mx;
    }
}

// |blend - fusion| for 8 px of one channel (a = px0-3, b = px4-7)
__device__ __forceinline__ float acc8(const float* __restrict__ wv,
                                      const float* __restrict__ wi,
                                      float4 va, float4 vb, float4 ra, float4 rb,
                                      float4 fa, float4 fb) {
    float s = 0.0f;
    s += fabsf(wv[0] * va.x + wi[0] * ra.x - fa.x);
    s += fabsf(wv[1] * va.y + wi[1] * ra.y - fa.y);
    s += fabsf(wv[2] * va.z + wi[2] * ra.z - fa.z);
    s += fabsf(wv[3] * va.w + wi[3] * ra.w - fa.w);
    s += fabsf(wv[4] * vb.x + wi[4] * rb.x - fb.x);
    s += fabsf(wv[5] * vb.y + wi[5] * rb.y - fb.y);
    s += fabsf(wv[6] * vb.z + wi[6] * rb.z - fb.z);
    s += fabsf(wv[7] * vb.w + wi[7] * rb.w - fb.w);
    return s;
}

// ---------------- K2: minmax finalize + blend + |diff| (gray recomputed, no q) ------
// one wave per image row: 42 independent float4 loads; center-row RGB doubles as
// blend input. Block = 4 waves = 4 consecutive rows. (proven-fast kernel.)
__global__ __launch_bounds__(256) void k_loss(const float* __restrict__ vis,
                                              const float* __restrict__ ir,
                                              const float* __restrict__ fus,
                                              const float* __restrict__ pm,
                                              float* __restrict__ partial, int B) {
    int w = threadIdx.x >> 6, lane = threadIdx.x & 63;
    int nwg = gridDim.x;
    int bid = (blockIdx.x & 7) * (nwg >> 3) + (blockIdx.x >> 3);  // bijective (nwg%8==0)
    int b = bid >> 7;
    int y = (bid & 127) * 4 + w;

    __shared__ float sred[4];
    {
        // finalize per-image min/max from 256 per-row-pair partials (4/lane)
        int src = w >> 1, qsel = w & 1;
        const float* base = pm + (size_t)(src * B + b) * RPP * 2;
        float v = base[lane * 2 + qsel];
        #pragma unroll
        for (int j = 1; j < 4; ++j) {
            float t = base[(lane + j * 64) * 2 + qsel];
            v = qsel ? fmaxf(v, t) : fminf(v, t);
        }
        if (qsel == 0) {
            #pragma unroll
            for (int o = 32; o > 0; o >>= 1) v = fminf(v, __shfl_down(v, o));
        } else {
            #pragma unroll
            for (int o = 32; o > 0; o >>= 1) v = fmaxf(v, __shfl_down(v, o));
        }
        if (lane == 0) sred[w] = v;
    }
    __syncthreads();
    float mn_v = sred[0], mx_v = sred[1], mn_i = sred[2], mx_i = sred[3];
    float inv_v = 1.0f / fmaxf(mx_v - mn_v, 1e-8f);
    float inv_i = 1.0f / fmaxf(mx_i - mn_i, 1e-8f);

    const float4* pv = (const float4*)(vis + (size_t)b * 3 * HW);
    const float4* pi = (const float4*)(ir  + (size_t)b * 3 * HW);
    const float4* pf = (const float4*)(fus + (size_t)b * 3 * HW);

    int o = y * (W / 4) + lane * 2;
    float4 vra = pv[o],                 vrb = pv[o + 1];
    float4 vga = pv[o + HW / 4],        vgb = pv[o + 1 + HW / 4];
    float4 vba = pv[o + 2 * (HW / 4)],  vbb = pv[o + 1 + 2 * (HW / 4)];
    float4 ira = pi[o],                 irb = pi[o + 1];
    float4 iga = pi[o + HW / 4],        igb = pi[o + 1 + HW / 4];
    float4 iba = pi[o + 2 * (HW / 4)],  ibb = pi[o + 1 + 2 * (HW / 4)];
    float4 fra = pf[o],                 frb = pf[o + 1];
    float4 fga = pf[o + HW / 4],        fgb = pf[o + 1 + HW / 4];
    float4 fba = pf[o + 2 * (HW / 4)],  fbb = pf[o + 1 + 2 * (HW / 4)];

    float mv[8], mi[8];
    {
        float g0[8], gm[8], gp[8];
        gray8f(vra, vrb, vga, vgb, vba, vbb, g0);
        grayrow(pv, refl(y - 1, H), lane, gm);
        grayrow(pv, refl(y + 1, H), lane, gp);
        float hm[10], h0[10], hp[10];
        win10(gm, lane, hm); win10(g0, lane, h0); win10(gp, lane, hp);
        sobel8(hm, h0, hp, mv);
    }
    {
        float g0[8], gm[8], gp[8];
        gray8f(ira, irb, iga, igb, iba, ibb, g0);
        grayrow(pi, refl(y - 1, H), lane, gm);
        grayrow(pi, refl(y + 1, H), lane, gp);
        float hm[10], h0[10], hp[10];
        win10(gm, lane, hm); win10(g0, lane, h0); win10(gp, lane, hp);
        sobel8(hm, h0, hp, mi);
    }

    float wv[8], wi[8];
    #pragma unroll
    for (int k = 0; k < 8; ++k) {
        float sv = (mv[k] - mn_v) * inv_v;
        float si = (mi[k] - mn_i) * inv_i;
        float den = sv + si + 1e-8f;
        float rden = 1.0f / den;
        wv[k] = sv * rden;
        wi[k] = si * rden;
    }

    float acc = 0.0f;
    acc += acc8(wv, wi, vra, vrb, ira, irb, fra, frb);
    acc += acc8(wv, wi, vga, vgb, iga, igb, fga, fgb);
    acc += acc8(wv, wi, vba, vbb, iba, ibb, fba, fbb);

    #pragma unroll
    for (int o2 = 32; o2 > 0; o2 >>= 1) acc += __shfl_down(acc, o2);
    __shared__ float ssum[4];
    if (lane == 0) ssum[w] = acc;
    __syncthreads();
    if (threadIdx.x == 0) partial[blockIdx.x] = ssum[0] + ssum[1] + ssum[2] + ssum[3];
}

// ---------------- K3: final reduce ----------------
__global__ void k_final(const float* __restrict__ partial, int n, float* __restrict__ out,
                        long long N) {
    double s = 0.0;
    for (int i = threadIdx.x; i < n; i += 256) s += (double)partial[i];
    __shared__ double sm[256];
    sm[threadIdx.x] = s;
    __syncthreads();
    for (int k = 128; k > 0; k >>= 1) {
        if (threadIdx.x < k) sm[threadIdx.x] += sm[threadIdx.x + k];
        __syncthreads();
    }
    if (threadIdx.x == 0) out[0] = (float)(sm[0] / (double)N);
}

extern "C" void kernel_launch(void* const* d_in, const int* in_sizes, int n_in,
                              void* d_out, int out_size, void* d_ws, size_t ws_size,
                              hipStream_t stream) {
    const float* vis = (const float*)d_in[0];
    const float* ir  = (const float*)d_in[1];
    const float* fus = (const float*)d_in[2];
    int B = in_sizes[0] / (3 * HW);  // 16

    float* pm      = (float*)d_ws;                   // 2*B*256*2 floats (64 KB)
    float* partial = pm + (size_t)2 * B * RPP * 2;   // 2048 floats
    float* out = (float*)d_out;

    int nblk_mm = 2 * B * RPP / 4;      // 2048 blocks x 4 waves, 2 rows/wave
    k_mm<<<nblk_mm, 256, 0, stream>>>(vis, ir, pm, B);

    int nblk_loss = B * H / 4;          // 2048 blocks x 4 waves (nwg%8==0)
    k_loss<<<nblk_loss, 256, 0, stream>>>(vis, ir, fus, pm, partial, B);

    k_final<<<1, 256, 0, stream>>>(partial, nblk_loss, out, (long long)B * 3 * HW);
}